// Round 6
// baseline (1875.288 us; speedup 1.0000x reference)
//
#include <hip/hip_runtime.h>
#include <hip/hip_bf16.h>
#include <stdint.h>

#define DM 1024
#define DF 4096
#define NE 8
#define TT 16384
#define MAXTILES 144          // 256-row tiles
#define CAP (MAXTILES * 256)  // 36864 padded rows max

typedef __bf16 bf16;
typedef __attribute__((ext_vector_type(8))) __bf16 bf16x8;
typedef __attribute__((ext_vector_type(4))) __bf16 bf16x4;
typedef __attribute__((ext_vector_type(4))) float f32x4;

#define AS1 __attribute__((address_space(1)))
#define AS3 __attribute__((address_space(3)))

__device__ __forceinline__ void async16(void* lds, const void* g) {
  __builtin_amdgcn_global_load_lds((const AS1 uint32_t*)g, (AS3 uint32_t*)lds, 16, 0, 0);
}

// ---------------- router: logits + top2 + softmax2 (pure f32, exact) --------
__global__ void k_gate(const float* __restrict__ x, const float* __restrict__ gw,
                       const float* __restrict__ gb,
                       int* __restrict__ sel, float* __restrict__ cw,
                       int* __restrict__ counts) {
  int gid = blockIdx.x * blockDim.x + threadIdx.x;
  int tok = gid >> 6;
  int lane = threadIdx.x & 63;
  const float* xr = x + (size_t)tok * DM;
  float l[8] = {0,0,0,0,0,0,0,0};
#pragma unroll
  for (int i = 0; i < DM / 64; i++) {
    int d = i * 64 + lane;
    float xv = xr[d];
    float4 gA = *(const float4*)(gw + d * 8);
    float4 gB = *(const float4*)(gw + d * 8 + 4);
    l[0] += xv * gA.x; l[1] += xv * gA.y; l[2] += xv * gA.z; l[3] += xv * gA.w;
    l[4] += xv * gB.x; l[5] += xv * gB.y; l[6] += xv * gB.z; l[7] += xv * gB.w;
  }
#pragma unroll
  for (int e = 0; e < 8; e++) {
    float v = l[e];
    v += __shfl_xor(v, 1);  v += __shfl_xor(v, 2);  v += __shfl_xor(v, 4);
    v += __shfl_xor(v, 8);  v += __shfl_xor(v, 16); v += __shfl_xor(v, 32);
    l[e] = v + gb[e];
  }
  if (lane == 0) {
    int e0 = 0;
#pragma unroll
    for (int e = 1; e < 8; e++) if (l[e] > l[e0]) e0 = e;
    int e1 = (e0 == 0) ? 1 : 0;
#pragma unroll
    for (int e = 0; e < 8; e++) if (e != e1 && e != e0 && l[e] > l[e1]) e1 = e;
    float t = expf(l[e1] - l[e0]);      // <= 1
    float c0 = 1.0f / (1.0f + t);
    float c1 = t / (1.0f + t);
    sel[2 * tok] = e0;  sel[2 * tok + 1] = e1;
    cw[2 * tok] = c0;   cw[2 * tok + 1] = c1;
    atomicAdd(&counts[e0], 1);
    atomicAdd(&counts[e1], 1);
  }
}

// meta layout (ints): [0..7]=counts [8..15]=cursors [16..23]=segment offsets
//                     [24]=ntiles [25]=total_padded
//                     [64 .. 64+MAXTILES)  = tile expert id
//                     [64+MAXTILES .. )    = tile row0 (padded global row)
__global__ void k_plan(int* __restrict__ meta, int* __restrict__ rows) {
  if (threadIdx.x == 0) {
    int off = 0, nt = 0;
    for (int e = 0; e < NE; e++) {
      meta[16 + e] = off;
      int c = meta[e];
      int ntile = (c + 255) >> 8;
      for (int j = 0; j < ntile; j++) {
        meta[64 + nt] = e;
        meta[64 + MAXTILES + nt] = off + j * 256;
        nt++;
      }
      off += ntile * 256;
    }
    meta[24] = nt;
    meta[25] = off;
  }
  __syncthreads();
  for (int i = threadIdx.x; i < CAP; i += blockDim.x) rows[i] = -1;
}

__global__ void k_scatter(const int* __restrict__ sel, const float* __restrict__ cw,
                          int* __restrict__ meta, int* __restrict__ rows,
                          float* __restrict__ coefs) {
  int t = blockIdx.x * blockDim.x + threadIdx.x;
  if (t >= TT) return;
#pragma unroll
  for (int k = 0; k < 2; k++) {
    int e = sel[2 * t + k];
    int idx = atomicAdd(&meta[8 + e], 1);
    int pos = meta[16 + e] + idx;
    rows[pos] = t;
    coefs[pos] = cw[2 * t + k];
  }
}

__global__ void k_gather(const float* __restrict__ x, const int* __restrict__ rows,
                         const int* __restrict__ meta, bf16* __restrict__ xg) {
  int pos = blockIdx.x;
  if (pos >= meta[25]) return;
  int t = rows[pos];
  int c = threadIdx.x * 4;
  bf16x4 o;
  if (t >= 0) {
    float4 f = *(const float4*)(x + (size_t)t * DM + c);
    o[0] = (bf16)f.x; o[1] = (bf16)f.y; o[2] = (bf16)f.z; o[3] = (bf16)f.w;
  } else {
    o[0] = (bf16)0.0f; o[1] = (bf16)0.0f; o[2] = (bf16)0.0f; o[3] = (bf16)0.0f;
  }
  *(bf16x4*)(xg + (size_t)pos * DM + c) = o;
}

// reads src[z*srcE + (r0+r)*srcRS + c0+c]  -> dst[z*dstE + (c0+c)*R + r0+r] bf16
__global__ void k_transcast(const float* __restrict__ src, bf16* __restrict__ dst,
                            int srcRS, size_t srcE, size_t dstE, int R) {
  __shared__ float tile[64][65];
  src += blockIdx.z * srcE;
  dst += blockIdx.z * dstE;
  int r0 = blockIdx.y * 64, c0 = blockIdx.x * 64;
  int tr = threadIdx.x >> 4;          // 0..15
  int tc = (threadIdx.x & 15) * 4;    // 0..60
#pragma unroll
  for (int i = 0; i < 4; i++) {
    int r = tr + i * 16;
    float4 f = *(const float4*)(src + (size_t)(r0 + r) * srcRS + (c0 + tc));
    tile[r][tc] = f.x; tile[r][tc + 1] = f.y; tile[r][tc + 2] = f.z; tile[r][tc + 3] = f.w;
  }
  __syncthreads();
#pragma unroll
  for (int i = 0; i < 4; i++) {
    int cc = tr + i * 16;             // output row = input col
    bf16x4 o;
    o[0] = (bf16)tile[tc + 0][cc];
    o[1] = (bf16)tile[tc + 1][cc];
    o[2] = (bf16)tile[tc + 2][cc];
    o[3] = (bf16)tile[tc + 3][cc];
    *(bf16x4*)(dst + (size_t)(c0 + cc) * R + (r0 + tc)) = o;
  }
}

// grouped GEMM: BM=256, BN=128, BK=64; 512 threads = 8 waves (4M x 2N),
// per-wave 64x64 output (acc[4][4] of 16x16 frags). 3-stage LDS ring,
// counted vmcnt pipeline (T3+T4), setprio around MFMA (T5), T2 XOR swizzle:
// LDS elem k8-chunk j of row r holds global chunk j^(r&7); staged linearly
// from pre-swizzled global source; ds_read applies the same XOR.
// Pipeline ledger: iteration t: barrier(A) [all waves done reading tile t-1]
//   -> issue stage(t+2) into buf (t+2)%3 == (t-1)%3  [safe]
//   -> vmcnt(12) [stages t+1,t+2 = 12 loads may remain -> tile t landed]
//   -> barrier(B) [every wave's portion of tile t landed]
//   -> compute tile t (no internal barriers).
// MODE 0: H[gr][n] = silu(acc + bias)  (bf16)
// MODE 1: atomicAdd(out[rows[gr]][n], coefs[gr] * (acc + addBias?bias:0))
template<int MODE>
__global__ __launch_bounds__(512, 1) void k_gemm(
    const bf16* __restrict__ A, const bf16* __restrict__ Bw,
    const float* __restrict__ bias, int bstride,
    bf16* __restrict__ H, float* __restrict__ Out, int addBias,
    const int* __restrict__ rows, const float* __restrict__ coefs,
    const int* __restrict__ meta, int KT, int NT) {
  int tidb = blockIdx.y;
  if (tidb >= meta[24]) return;
  int e = meta[64 + tidb];
  int row0 = meta[64 + MAXTILES + tidb];
  int n0 = blockIdx.x * 128;

  __shared__ __align__(16) bf16 As[3][256 * 64];   // 96 KiB
  __shared__ __align__(16) bf16 Bs[3][128 * 64];   // 48 KiB

  int t = threadIdx.x;              // 0..511
  int lane = t & 63;
  int w = t >> 6;                   // 0..7
  int wm = w >> 1, wn = w & 1;      // 4M x 2N

  // staging map: chunk c = t + i*512 -> row = c>>3 (A: +0/64/128/192, B: +0/64),
  // global k-chunk = (t&7) ^ (row&7)  (pre-swizzled source), LDS linear at c*8.
  int arow = t >> 3;                // 0..63
  int k8 = ((t & 7) ^ (arow & 7)) * 8;
  const bf16* Ab = A + (size_t)(row0 + arow) * KT + k8;
  const bf16* Bb = Bw + ((size_t)e * NT + n0 + arow) * KT + k8;
  size_t rstep = (size_t)64 * KT;
  int ldso = t * 8;                 // element offset

  f32x4 acc[4][4] = {};

  auto stage = [&](int kt, int buf) {
    const bf16* a = Ab + kt;
    const bf16* b = Bb + kt;
    bf16* la = &As[buf][ldso];
    bf16* lb = &Bs[buf][ldso];
    async16(la,         a);
    async16(la + 4096,  a + rstep);
    async16(la + 8192,  a + 2 * rstep);
    async16(la + 12288, a + 3 * rstep);
    async16(lb,         b);
    async16(lb + 4096,  b + rstep);
  };

  auto compute = [&](int buf) {
#pragma unroll
    for (int ks = 0; ks < 2; ks++) {
      int kx = (ks * 32 + ((lane >> 4) * 8)) ^ ((lane & 7) * 8);
      bf16x8 af[4], bfr[4];
#pragma unroll
      for (int mi = 0; mi < 4; mi++)
        af[mi] = *(const bf16x8*)&As[buf][(wm * 64 + mi * 16 + (lane & 15)) * 64 + kx];
#pragma unroll
      for (int ni = 0; ni < 4; ni++)
        bfr[ni] = *(const bf16x8*)&Bs[buf][(wn * 64 + ni * 16 + (lane & 15)) * 64 + kx];
      __builtin_amdgcn_s_setprio(1);
#pragma unroll
      for (int mi = 0; mi < 4; mi++)
#pragma unroll
        for (int ni = 0; ni < 4; ni++)
          acc[mi][ni] = __builtin_amdgcn_mfma_f32_16x16x32_bf16(af[mi], bfr[ni], acc[mi][ni], 0, 0, 0);
      __builtin_amdgcn_s_setprio(0);
    }
  };

  int nt = KT >> 6;                 // >= 8 always here
  stage(0, 0);
  stage(64, 1);
  int cur = 0;
  for (int ti = 0; ti < nt - 2; ti++) {
    __builtin_amdgcn_s_barrier();                       // (A)
    stage((ti + 2) << 6, cur == 0 ? 2 : cur - 1);       // buf (ti+2)%3
    asm volatile("s_waitcnt vmcnt(12)" ::: "memory");
    __builtin_amdgcn_s_barrier();                       // (B)
    compute(cur);
    cur = (cur == 2) ? 0 : cur + 1;
  }
  __builtin_amdgcn_s_barrier();
  asm volatile("s_waitcnt vmcnt(6)" ::: "memory");
  __builtin_amdgcn_s_barrier();
  compute(cur);
  cur = (cur == 2) ? 0 : cur + 1;
  __builtin_amdgcn_s_barrier();
  asm volatile("s_waitcnt vmcnt(0)" ::: "memory");
  __builtin_amdgcn_s_barrier();
  compute(cur);

  int rq = (lane >> 4) * 4;
  int cq = lane & 15;
  float bv[4];
#pragma unroll
  for (int ni = 0; ni < 4; ni++)
    bv[ni] = bias[e * bstride + n0 + wn * 64 + ni * 16 + cq];

  if (MODE == 0) {
#pragma unroll
    for (int mi = 0; mi < 4; mi++) {
#pragma unroll
      for (int i = 0; i < 4; i++) {
        int gr = row0 + wm * 64 + mi * 16 + rq + i;
        bf16* hr = H + (size_t)gr * NT + n0 + wn * 64;
#pragma unroll
        for (int ni = 0; ni < 4; ni++) {
          float v = acc[mi][ni][i] + bv[ni];
          float s = v / (1.0f + __expf(-v));
          hr[ni * 16 + cq] = (bf16)s;
        }
      }
    }
  } else {
#pragma unroll
    for (int mi = 0; mi < 4; mi++) {
#pragma unroll
      for (int i = 0; i < 4; i++) {
        int gr = row0 + wm * 64 + mi * 16 + rq + i;
        int trow = rows[gr];
        if (trow < 0) continue;
        float cf = coefs[gr];
        float* orow = Out + (size_t)trow * DM + n0 + wn * 64;
#pragma unroll
        for (int ni = 0; ni < 4; ni++) {
          float v = acc[mi][ni][i];
          if (addBias) v += bv[ni];
          atomicAdd(&orow[ni * 16 + cq], cf * v);
        }
      }
    }
  }
}

extern "C" void kernel_launch(void* const* d_in, const int* in_sizes, int n_in,
                              void* d_out, int out_size, void* d_ws, size_t ws_size,
                              hipStream_t stream) {
  const float* x  = (const float*)d_in[0];
  const float* gw = (const float*)d_in[1];
  const float* gb = (const float*)d_in[2];
  const float* w1 = (const float*)d_in[3];
  const float* b1 = (const float*)d_in[4];
  const float* w2 = (const float*)d_in[5];
  const float* b2 = (const float*)d_in[6];
  float* out = (float*)d_out;

  // pick DF chunking so the workspace plan fits ws_size
  size_t smallB = (size_t)CAP * 4 * 2 + (size_t)TT * 2 * 4 * 2 + 8192 + 16 * 256;
  int nc = 8;
  for (int cand = 1; cand <= 8; cand <<= 1) {
    size_t dfc = DF / cand;
    size_t need = 2 * ((size_t)NE * dfc * DM * 2)   // w1tc + w2tc
                + (size_t)CAP * DM * 2              // xg
                + (size_t)CAP * dfc * 2             // h
                + smallB;
    if (need <= ws_size) { nc = cand; break; }
  }
  const int DFC = DF / nc;

  char* ws = (char*)d_ws;
  size_t off = 0;
  auto alloc = [&](size_t bytes) -> void* {
    void* p = ws + off;
    off += (bytes + 255) & ~(size_t)255;
    return p;
  };
  bf16* w1tc = (bf16*)alloc((size_t)NE * DFC * DM * 2);  // [E][DFC][DM]
  bf16* w2tc = (bf16*)alloc((size_t)NE * DM * DFC * 2);  // [E][DM][DFC]
  bf16* xg   = (bf16*)alloc((size_t)CAP * DM * 2);
  bf16* h    = (bf16*)alloc((size_t)CAP * DFC * 2);
  int* rows  = (int*)alloc((size_t)CAP * 4);
  float* cof = (float*)alloc((size_t)CAP * 4);
  int* sel   = (int*)alloc((size_t)TT * 2 * 4);
  float* cw  = (float*)alloc((size_t)TT * 2 * 4);
  int* meta  = (int*)alloc(8192);

  hipMemsetAsync(meta, 0, 256, stream);
  hipMemsetAsync(out, 0, (size_t)out_size * sizeof(float), stream);
  k_gate<<<TT / 4, 256, 0, stream>>>(x, gw, gb, sel, cw, meta);
  k_plan<<<1, 256, 0, stream>>>(meta, rows);
  k_scatter<<<TT / 256, 256, 0, stream>>>(sel, cw, meta, rows, cof);
  k_gather<<<CAP, 256, 0, stream>>>(x, rows, meta, xg);

  for (int c = 0; c < nc; c++) {
    const float* w1c = w1 + (size_t)c * DFC;        // [E][DM][DF] cols c*DFC..
    const float* w2c = w2 + (size_t)c * DFC * DM;   // [E][DF][DM] rows c*DFC..
    // w1 chunk: R=DM rows, DFC cols -> w1tc [E][DFC][DM]
    k_transcast<<<dim3(DFC / 64, DM / 64, NE), 256, 0, stream>>>(
        w1c, w1tc, DF, (size_t)DM * DF, (size_t)DFC * DM, DM);
    // w2 chunk: R=DFC rows, DM cols -> w2tc [E][DM][DFC]
    k_transcast<<<dim3(DM / 64, DFC / 64, NE), 256, 0, stream>>>(
        w2c, w2tc, DM, (size_t)DF * DM, (size_t)DM * DFC, DFC);
    // GEMM1: xg [CAP x DM] @ w1tc^T -> h (silu), N=DFC
    k_gemm<0><<<dim3(DFC / 128, MAXTILES), 512, 0, stream>>>(
        xg, w1tc, b1 + (size_t)c * DFC, DF, h, nullptr, 0, rows, cof, meta, DM, DFC);
    // GEMM2: h [CAP x DFC] @ w2tc^T -> atomic out, N=DM
    k_gemm<1><<<dim3(DM / 128, MAXTILES), 512, 0, stream>>>(
        h, w2tc, b2, DM, nullptr, out, (c == 0) ? 1 : 0, rows, cof, meta, DFC, DM);
  }
}

// Round 7
// 1680.255 us; speedup vs baseline: 1.1161x; 1.1161x over previous
//
#include <hip/hip_runtime.h>
#include <hip/hip_bf16.h>
#include <stdint.h>

#define DM 1024
#define DF 4096
#define NE 8
#define TT 16384
#define MAXTILES 144          // 256-row tiles
#define CAP (MAXTILES * 256)  // 36864 padded rows max

typedef __bf16 bf16;
typedef __attribute__((ext_vector_type(8))) __bf16 bf16x8;
typedef __attribute__((ext_vector_type(4))) __bf16 bf16x4;
typedef __attribute__((ext_vector_type(4))) float f32x4;

#define AS1 __attribute__((address_space(1)))
#define AS3 __attribute__((address_space(3)))

__device__ __forceinline__ void async16(void* lds, const void* g) {
  __builtin_amdgcn_global_load_lds((const AS1 uint32_t*)g, (AS3 uint32_t*)lds, 16, 0, 0);
}

// ---------------- router: logits + top2 + softmax2 (pure f32, exact) --------
__global__ void k_gate(const float* __restrict__ x, const float* __restrict__ gw,
                       const float* __restrict__ gb,
                       int* __restrict__ sel, float* __restrict__ cw,
                       int* __restrict__ counts) {
  int gid = blockIdx.x * blockDim.x + threadIdx.x;
  int tok = gid >> 6;
  int lane = threadIdx.x & 63;
  const float* xr = x + (size_t)tok * DM;
  float l[8] = {0,0,0,0,0,0,0,0};
#pragma unroll
  for (int i = 0; i < DM / 64; i++) {
    int d = i * 64 + lane;
    float xv = xr[d];
    float4 gA = *(const float4*)(gw + d * 8);
    float4 gB = *(const float4*)(gw + d * 8 + 4);
    l[0] += xv * gA.x; l[1] += xv * gA.y; l[2] += xv * gA.z; l[3] += xv * gA.w;
    l[4] += xv * gB.x; l[5] += xv * gB.y; l[6] += xv * gB.z; l[7] += xv * gB.w;
  }
#pragma unroll
  for (int e = 0; e < 8; e++) {
    float v = l[e];
    v += __shfl_xor(v, 1);  v += __shfl_xor(v, 2);  v += __shfl_xor(v, 4);
    v += __shfl_xor(v, 8);  v += __shfl_xor(v, 16); v += __shfl_xor(v, 32);
    l[e] = v + gb[e];
  }
  if (lane == 0) {
    int e0 = 0;
#pragma unroll
    for (int e = 1; e < 8; e++) if (l[e] > l[e0]) e0 = e;
    int e1 = (e0 == 0) ? 1 : 0;
#pragma unroll
    for (int e = 0; e < 8; e++) if (e != e1 && e != e0 && l[e] > l[e1]) e1 = e;
    float t = expf(l[e1] - l[e0]);      // <= 1
    float c0 = 1.0f / (1.0f + t);
    float c1 = t / (1.0f + t);
    sel[2 * tok] = e0;  sel[2 * tok + 1] = e1;
    cw[2 * tok] = c0;   cw[2 * tok + 1] = c1;
    atomicAdd(&counts[e0], 1);
    atomicAdd(&counts[e1], 1);
  }
}

// meta layout (ints): [0..7]=counts [8..15]=cursors [16..23]=segment offsets
//                     [24]=ntiles [25]=total_padded
//                     [64 .. 64+MAXTILES)  = tile expert id
//                     [64+MAXTILES .. )    = tile row0 (padded global row)
__global__ void k_plan(int* __restrict__ meta, int* __restrict__ rows) {
  if (threadIdx.x == 0) {
    int off = 0, nt = 0;
    for (int e = 0; e < NE; e++) {
      meta[16 + e] = off;
      int c = meta[e];
      int ntile = (c + 255) >> 8;
      for (int j = 0; j < ntile; j++) {
        meta[64 + nt] = e;
        meta[64 + MAXTILES + nt] = off + j * 256;
        nt++;
      }
      off += ntile * 256;
    }
    meta[24] = nt;
    meta[25] = off;
  }
  __syncthreads();
  for (int i = threadIdx.x; i < CAP; i += blockDim.x) rows[i] = -1;
}

__global__ void k_scatter(const int* __restrict__ sel, const float* __restrict__ cw,
                          int* __restrict__ meta, int* __restrict__ rows,
                          float* __restrict__ coefs) {
  int t = blockIdx.x * blockDim.x + threadIdx.x;
  if (t >= TT) return;
#pragma unroll
  for (int k = 0; k < 2; k++) {
    int e = sel[2 * t + k];
    int idx = atomicAdd(&meta[8 + e], 1);
    int pos = meta[16 + e] + idx;
    rows[pos] = t;
    coefs[pos] = cw[2 * t + k];
  }
}

__global__ void k_gather(const float* __restrict__ x, const int* __restrict__ rows,
                         const int* __restrict__ meta, bf16* __restrict__ xg) {
  int pos = blockIdx.x;
  if (pos >= meta[25]) return;
  int t = rows[pos];
  int c = threadIdx.x * 4;
  bf16x4 o;
  if (t >= 0) {
    float4 f = *(const float4*)(x + (size_t)t * DM + c);
    o[0] = (bf16)f.x; o[1] = (bf16)f.y; o[2] = (bf16)f.z; o[3] = (bf16)f.w;
  } else {
    o[0] = (bf16)0.0f; o[1] = (bf16)0.0f; o[2] = (bf16)0.0f; o[3] = (bf16)0.0f;
  }
  *(bf16x4*)(xg + (size_t)pos * DM + c) = o;
}

// reads src[z*srcE + (r0+r)*srcRS + c0+c]  -> dst[z*dstE + (c0+c)*R + r0+r] bf16
__global__ void k_transcast(const float* __restrict__ src, bf16* __restrict__ dst,
                            int srcRS, size_t srcE, size_t dstE, int R) {
  __shared__ float tile[64][65];
  src += blockIdx.z * srcE;
  dst += blockIdx.z * dstE;
  int r0 = blockIdx.y * 64, c0 = blockIdx.x * 64;
  int tr = threadIdx.x >> 4;          // 0..15
  int tc = (threadIdx.x & 15) * 4;    // 0..60
#pragma unroll
  for (int i = 0; i < 4; i++) {
    int r = tr + i * 16;
    float4 f = *(const float4*)(src + (size_t)(r0 + r) * srcRS + (c0 + tc));
    tile[r][tc] = f.x; tile[r][tc + 1] = f.y; tile[r][tc + 2] = f.z; tile[r][tc + 3] = f.w;
  }
  __syncthreads();
#pragma unroll
  for (int i = 0; i < 4; i++) {
    int cc = tr + i * 16;             // output row = input col
    bf16x4 o;
    o[0] = (bf16)tile[tc + 0][cc];
    o[1] = (bf16)tile[tc + 1][cc];
    o[2] = (bf16)tile[tc + 2][cc];
    o[3] = (bf16)tile[tc + 3][cc];
    *(bf16x4*)(dst + (size_t)(c0 + cc) * R + (r0 + tc)) = o;
  }
}

// grouped GEMM: BM=256, BN=256, BK=64; 512 threads = 8 waves (2M x 4N),
// per-wave 128x64 output = acc[8][4] 16x16 frags. Double-buffered LDS
// (128 KiB), interleaved schedule: stage(t+1) issued at top of iter t
// (full-iteration latency cover), then 4 phases of ds_read+16 MFMA with
// setprio (T5). One raw s_barrier + vmcnt(0) per K-tile.
// T2 swizzle: LDS chunk c8 of row r holds global k-chunk c8^(r&7); staged
// linearly from pre-swizzled global source; ds_read applies the same XOR.
// Ledger: reads of buf b in iter t complete before each wave's barrier
// (lgkm-drained before MFMA); stage into buf b happens only after the
// barrier of iter t+1 (sched_barrier(0) pins it); RAW on tile t+1 covered
// by vmcnt(0)+barrier at top of iter t+1.
// MODE 0: H[gr][n] = silu(acc + bias)  (bf16)
// MODE 1: atomicAdd(out[rows[gr]][n], coefs[gr] * (acc + addBias?bias:0))
template<int MODE>
__global__ __launch_bounds__(512, 2) void k_gemm(
    const bf16* __restrict__ A, const bf16* __restrict__ Bw,
    const float* __restrict__ bias, int bstride,
    bf16* __restrict__ H, float* __restrict__ Out, int addBias,
    const int* __restrict__ rows, const float* __restrict__ coefs,
    const int* __restrict__ meta, int KT, int NT) {
  int tidb = blockIdx.y;
  if (tidb >= meta[24]) return;
  int e = meta[64 + tidb];
  int row0 = meta[64 + MAXTILES + tidb];
  int n0 = blockIdx.x * 256;

  __shared__ __align__(16) bf16 As[2][256 * 64];   // 64 KiB
  __shared__ __align__(16) bf16 Bs[2][256 * 64];   // 64 KiB

  int t = threadIdx.x;              // 0..511
  int lane = t & 63;
  int w = t >> 6;                   // 0..7
  int wm = w >> 2, wn = w & 3;      // 2M x 4N

  // staging: 8 chunks/thread; chunk i covers row arow+64i, global k-chunk
  // (t&7)^(row&7) (pre-swizzled source), LDS linear at (t + i*512)*16B.
  int arow = t >> 3;                // 0..63
  int k8 = ((t & 7) ^ (arow & 7)) * 8;
  const bf16* Ab = A + (size_t)(row0 + arow) * KT + k8;
  const bf16* Bb = Bw + ((size_t)e * NT + n0 + arow) * KT + k8;
  size_t rstep = (size_t)64 * KT;
  int ldso = t * 8;                 // element offset

  f32x4 acc[8][4] = {};

  auto stage = [&](int kt, int buf) {
    const bf16* a = Ab + kt;
    const bf16* b = Bb + kt;
    bf16* la = &As[buf][ldso];
    bf16* lb = &Bs[buf][ldso];
    async16(la,         a);
    async16(la + 4096,  a + rstep);
    async16(la + 8192,  a + 2 * rstep);
    async16(la + 12288, a + 3 * rstep);
    async16(lb,         b);
    async16(lb + 4096,  b + rstep);
    async16(lb + 8192,  b + 2 * rstep);
    async16(lb + 12288, b + 3 * rstep);
  };

  int rA = (wm * 128 + (lane & 15)) * 64;   // wave A base row * 64
  int rB = (wn * 64 + (lane & 15)) * 64;    // wave B base row * 64
  int kx0 = ((lane >> 4) * 8) ^ ((lane & 7) * 8);
  int kx1 = kx0 ^ 32;

  auto compute = [&](int buf) {
    const bf16* Ap = &As[buf][rA];
    const bf16* Bp = &Bs[buf][rB];
    bf16x8 af[4], bfr[4];
    // phase 0: ks0, B all + A mi 0..3
#pragma unroll
    for (int ni = 0; ni < 4; ni++) bfr[ni] = *(const bf16x8*)&Bp[ni * 1024 + kx0];
#pragma unroll
    for (int mi = 0; mi < 4; mi++) af[mi] = *(const bf16x8*)&Ap[mi * 1024 + kx0];
    __builtin_amdgcn_s_setprio(1);
#pragma unroll
    for (int mi = 0; mi < 4; mi++)
#pragma unroll
      for (int ni = 0; ni < 4; ni++)
        acc[mi][ni] = __builtin_amdgcn_mfma_f32_16x16x32_bf16(af[mi], bfr[ni], acc[mi][ni], 0, 0, 0);
    __builtin_amdgcn_s_setprio(0);
    // phase 1: ks0, A mi 4..7 (reuse bfr)
#pragma unroll
    for (int mi = 0; mi < 4; mi++) af[mi] = *(const bf16x8*)&Ap[(mi + 4) * 1024 + kx0];
    __builtin_amdgcn_s_setprio(1);
#pragma unroll
    for (int mi = 0; mi < 4; mi++)
#pragma unroll
      for (int ni = 0; ni < 4; ni++)
        acc[mi + 4][ni] = __builtin_amdgcn_mfma_f32_16x16x32_bf16(af[mi], bfr[ni], acc[mi + 4][ni], 0, 0, 0);
    __builtin_amdgcn_s_setprio(0);
    // phase 2: ks1, B all + A mi 0..3
#pragma unroll
    for (int ni = 0; ni < 4; ni++) bfr[ni] = *(const bf16x8*)&Bp[ni * 1024 + kx1];
#pragma unroll
    for (int mi = 0; mi < 4; mi++) af[mi] = *(const bf16x8*)&Ap[mi * 1024 + kx1];
    __builtin_amdgcn_s_setprio(1);
#pragma unroll
    for (int mi = 0; mi < 4; mi++)
#pragma unroll
      for (int ni = 0; ni < 4; ni++)
        acc[mi][ni] = __builtin_amdgcn_mfma_f32_16x16x32_bf16(af[mi], bfr[ni], acc[mi][ni], 0, 0, 0);
    __builtin_amdgcn_s_setprio(0);
    // phase 3: ks1, A mi 4..7
#pragma unroll
    for (int mi = 0; mi < 4; mi++) af[mi] = *(const bf16x8*)&Ap[(mi + 4) * 1024 + kx1];
    __builtin_amdgcn_s_setprio(1);
#pragma unroll
    for (int mi = 0; mi < 4; mi++)
#pragma unroll
      for (int ni = 0; ni < 4; ni++)
        acc[mi + 4][ni] = __builtin_amdgcn_mfma_f32_16x16x32_bf16(af[mi], bfr[ni], acc[mi + 4][ni], 0, 0, 0);
    __builtin_amdgcn_s_setprio(0);
  };

  int nt = KT >> 6;
  stage(0, 0);
  for (int ti = 0; ti < nt; ti++) {
    int buf = ti & 1;
    asm volatile("s_waitcnt vmcnt(0)" ::: "memory");
    __builtin_amdgcn_s_barrier();
    __builtin_amdgcn_sched_barrier(0);
    if (ti + 1 < nt) stage((ti + 1) << 6, buf ^ 1);
    compute(buf);
  }

  int rq = (lane >> 4) * 4;
  int cq = lane & 15;
  float bv[4];
#pragma unroll
  for (int ni = 0; ni < 4; ni++)
    bv[ni] = bias[e * bstride + n0 + wn * 64 + ni * 16 + cq];

  if (MODE == 0) {
#pragma unroll
    for (int mi = 0; mi < 8; mi++) {
#pragma unroll
      for (int i = 0; i < 4; i++) {
        int gr = row0 + wm * 128 + mi * 16 + rq + i;
        bf16* hr = H + (size_t)gr * NT + n0 + wn * 64;
#pragma unroll
        for (int ni = 0; ni < 4; ni++) {
          float v = acc[mi][ni][i] + bv[ni];
          float s = v / (1.0f + __expf(-v));
          hr[ni * 16 + cq] = (bf16)s;
        }
      }
    }
  } else {
#pragma unroll
    for (int mi = 0; mi < 8; mi++) {
#pragma unroll
      for (int i = 0; i < 4; i++) {
        int gr = row0 + wm * 128 + mi * 16 + rq + i;
        int trow = rows[gr];
        if (trow < 0) continue;
        float cf = coefs[gr];
        float* orow = Out + (size_t)trow * DM + n0 + wn * 64;
#pragma unroll
        for (int ni = 0; ni < 4; ni++) {
          float v = acc[mi][ni][i];
          if (addBias) v += bv[ni];
          atomicAdd(&orow[ni * 16 + cq], cf * v);
        }
      }
    }
  }
}

extern "C" void kernel_launch(void* const* d_in, const int* in_sizes, int n_in,
                              void* d_out, int out_size, void* d_ws, size_t ws_size,
                              hipStream_t stream) {
  const float* x  = (const float*)d_in[0];
  const float* gw = (const float*)d_in[1];
  const float* gb = (const float*)d_in[2];
  const float* w1 = (const float*)d_in[3];
  const float* b1 = (const float*)d_in[4];
  const float* w2 = (const float*)d_in[5];
  const float* b2 = (const float*)d_in[6];
  float* out = (float*)d_out;

  // pick DF chunking so the workspace plan fits ws_size
  size_t smallB = (size_t)CAP * 4 * 2 + (size_t)TT * 2 * 4 * 2 + 8192 + 16 * 256;
  int nc = 8;
  for (int cand = 1; cand <= 8; cand <<= 1) {
    size_t dfc = DF / cand;
    size_t need = 2 * ((size_t)NE * dfc * DM * 2)   // w1tc + w2tc
                + (size_t)CAP * DM * 2              // xg
                + (size_t)CAP * dfc * 2             // h
                + smallB;
    if (need <= ws_size) { nc = cand; break; }
  }
  const int DFC = DF / nc;

  char* ws = (char*)d_ws;
  size_t off = 0;
  auto alloc = [&](size_t bytes) -> void* {
    void* p = ws + off;
    off += (bytes + 255) & ~(size_t)255;
    return p;
  };
  bf16* w1tc = (bf16*)alloc((size_t)NE * DFC * DM * 2);  // [E][DFC][DM]
  bf16* w2tc = (bf16*)alloc((size_t)NE * DM * DFC * 2);  // [E][DM][DFC]
  bf16* xg   = (bf16*)alloc((size_t)CAP * DM * 2);
  bf16* h    = (bf16*)alloc((size_t)CAP * DFC * 2);
  int* rows  = (int*)alloc((size_t)CAP * 4);
  float* cof = (float*)alloc((size_t)CAP * 4);
  int* sel   = (int*)alloc((size_t)TT * 2 * 4);
  float* cw  = (float*)alloc((size_t)TT * 2 * 4);
  int* meta  = (int*)alloc(8192);

  hipMemsetAsync(meta, 0, 256, stream);
  hipMemsetAsync(out, 0, (size_t)out_size * sizeof(float), stream);
  k_gate<<<TT / 4, 256, 0, stream>>>(x, gw, gb, sel, cw, meta);
  k_plan<<<1, 256, 0, stream>>>(meta, rows);
  k_scatter<<<TT / 256, 256, 0, stream>>>(sel, cw, meta, rows, cof);
  k_gather<<<CAP, 256, 0, stream>>>(x, rows, meta, xg);

  for (int c = 0; c < nc; c++) {
    const float* w1c = w1 + (size_t)c * DFC;        // [E][DM][DF] cols c*DFC..
    const float* w2c = w2 + (size_t)c * DFC * DM;   // [E][DF][DM] rows c*DFC..
    // w1 chunk: R=DM rows, DFC cols -> w1tc [E][DFC][DM]
    k_transcast<<<dim3(DFC / 64, DM / 64, NE), 256, 0, stream>>>(
        w1c, w1tc, DF, (size_t)DM * DF, (size_t)DFC * DM, DM);
    // w2 chunk: R=DFC rows, DM cols -> w2tc [E][DM][DFC]
    k_transcast<<<dim3(DM / 64, DFC / 64, NE), 256, 0, stream>>>(
        w2c, w2tc, DM, (size_t)DF * DM, (size_t)DM * DFC, DFC);
    // GEMM1: xg [CAP x DM] @ w1tc^T -> h (silu), N=DFC
    k_gemm<0><<<dim3(DFC / 256, MAXTILES), 512, 0, stream>>>(
        xg, w1tc, b1 + (size_t)c * DFC, DF, h, nullptr, 0, rows, cof, meta, DM, DFC);
    // GEMM2: h [CAP x DFC] @ w2tc^T -> atomic out, N=DM
    k_gemm<1><<<dim3(DM / 256, MAXTILES), 512, 0, stream>>>(
        h, w2tc, b2, DM, nullptr, out, (c == 0) ? 1 : 0, rows, cof, meta, DFC, DM);
  }
}

// Round 9
// 1475.554 us; speedup vs baseline: 1.2709x; 1.1387x over previous
//
#include <hip/hip_runtime.h>
#include <hip/hip_bf16.h>
#include <stdint.h>

#define DM 1024
#define DF 4096
#define NE 8
#define TT 16384
#define MAXTILES 144          // 256-row tiles
#define CAP (MAXTILES * 256)  // 36864 padded rows max

typedef __bf16 bf16;
typedef __attribute__((ext_vector_type(8))) __bf16 bf16x8;
typedef __attribute__((ext_vector_type(4))) __bf16 bf16x4;
typedef __attribute__((ext_vector_type(4))) float f32x4;

#define AS1 __attribute__((address_space(1)))
#define AS3 __attribute__((address_space(3)))

__device__ __forceinline__ void async16(void* lds, const void* g) {
  __builtin_amdgcn_global_load_lds((const AS1 uint32_t*)g, (AS3 uint32_t*)lds, 16, 0, 0);
}

// ---------------- router: logits + top2 + softmax2 (pure f32, exact) --------
__global__ void k_gate(const float* __restrict__ x, const float* __restrict__ gw,
                       const float* __restrict__ gb,
                       int* __restrict__ sel, float* __restrict__ cw,
                       int* __restrict__ counts) {
  int gid = blockIdx.x * blockDim.x + threadIdx.x;
  int tok = gid >> 6;
  int lane = threadIdx.x & 63;
  const float* xr = x + (size_t)tok * DM;
  float l[8] = {0,0,0,0,0,0,0,0};
#pragma unroll
  for (int i = 0; i < DM / 64; i++) {
    int d = i * 64 + lane;
    float xv = xr[d];
    float4 gA = *(const float4*)(gw + d * 8);
    float4 gB = *(const float4*)(gw + d * 8 + 4);
    l[0] += xv * gA.x; l[1] += xv * gA.y; l[2] += xv * gA.z; l[3] += xv * gA.w;
    l[4] += xv * gB.x; l[5] += xv * gB.y; l[6] += xv * gB.z; l[7] += xv * gB.w;
  }
#pragma unroll
  for (int e = 0; e < 8; e++) {
    float v = l[e];
    v += __shfl_xor(v, 1);  v += __shfl_xor(v, 2);  v += __shfl_xor(v, 4);
    v += __shfl_xor(v, 8);  v += __shfl_xor(v, 16); v += __shfl_xor(v, 32);
    l[e] = v + gb[e];
  }
  if (lane == 0) {
    int e0 = 0;
#pragma unroll
    for (int e = 1; e < 8; e++) if (l[e] > l[e0]) e0 = e;
    int e1 = (e0 == 0) ? 1 : 0;
#pragma unroll
    for (int e = 0; e < 8; e++) if (e != e1 && e != e0 && l[e] > l[e1]) e1 = e;
    float t = expf(l[e1] - l[e0]);      // <= 1
    float c0 = 1.0f / (1.0f + t);
    float c1 = t / (1.0f + t);
    sel[2 * tok] = e0;  sel[2 * tok + 1] = e1;
    cw[2 * tok] = c0;   cw[2 * tok + 1] = c1;
    atomicAdd(&counts[e0], 1);
    atomicAdd(&counts[e1], 1);
  }
}

// meta layout (ints): [0..7]=counts [8..15]=cursors [16..23]=segment offsets
//                     [24]=ntiles [25]=total_padded
//                     [64 .. 64+MAXTILES)  = tile expert id
//                     [64+MAXTILES .. )    = tile row0 (padded global row)
__global__ void k_plan(int* __restrict__ meta, int* __restrict__ rows) {
  if (threadIdx.x == 0) {
    int off = 0, nt = 0;
    for (int e = 0; e < NE; e++) {
      meta[16 + e] = off;
      int c = meta[e];
      int ntile = (c + 255) >> 8;
      for (int j = 0; j < ntile; j++) {
        meta[64 + nt] = e;
        meta[64 + MAXTILES + nt] = off + j * 256;
        nt++;
      }
      off += ntile * 256;
    }
    meta[24] = nt;
    meta[25] = off;
  }
  __syncthreads();
  for (int i = threadIdx.x; i < CAP; i += blockDim.x) rows[i] = -1;
}

__global__ void k_scatter(const int* __restrict__ sel, const float* __restrict__ cw,
                          int* __restrict__ meta, int* __restrict__ rows,
                          float* __restrict__ coefs) {
  int t = blockIdx.x * blockDim.x + threadIdx.x;
  if (t >= TT) return;
#pragma unroll
  for (int k = 0; k < 2; k++) {
    int e = sel[2 * t + k];
    int idx = atomicAdd(&meta[8 + e], 1);
    int pos = meta[16 + e] + idx;
    rows[pos] = t;
    coefs[pos] = cw[2 * t + k];
  }
}

__global__ void k_gather(const float* __restrict__ x, const int* __restrict__ rows,
                         const int* __restrict__ meta, bf16* __restrict__ xg) {
  int pos = blockIdx.x;
  if (pos >= meta[25]) return;
  int t = rows[pos];
  int c = threadIdx.x * 4;
  bf16x4 o;
  if (t >= 0) {
    float4 f = *(const float4*)(x + (size_t)t * DM + c);
    o[0] = (bf16)f.x; o[1] = (bf16)f.y; o[2] = (bf16)f.z; o[3] = (bf16)f.w;
  } else {
    o[0] = (bf16)0.0f; o[1] = (bf16)0.0f; o[2] = (bf16)0.0f; o[3] = (bf16)0.0f;
  }
  *(bf16x4*)(xg + (size_t)pos * DM + c) = o;
}

// reads src[z*srcE + (r0+r)*srcRS + c0+c]  -> dst[z*dstE + (c0+c)*R + r0+r] bf16
__global__ void k_transcast(const float* __restrict__ src, bf16* __restrict__ dst,
                            int srcRS, size_t srcE, size_t dstE, int R) {
  __shared__ float tile[64][65];
  src += blockIdx.z * srcE;
  dst += blockIdx.z * dstE;
  int r0 = blockIdx.y * 64, c0 = blockIdx.x * 64;
  int tr = threadIdx.x >> 4;          // 0..15
  int tc = (threadIdx.x & 15) * 4;    // 0..60
#pragma unroll
  for (int i = 0; i < 4; i++) {
    int r = tr + i * 16;
    float4 f = *(const float4*)(src + (size_t)(r0 + r) * srcRS + (c0 + tc));
    tile[r][tc] = f.x; tile[r][tc + 1] = f.y; tile[r][tc + 2] = f.z; tile[r][tc + 3] = f.w;
  }
  __syncthreads();
#pragma unroll
  for (int i = 0; i < 4; i++) {
    int cc = tr + i * 16;             // output row = input col
    bf16x4 o;
    o[0] = (bf16)tile[tc + 0][cc];
    o[1] = (bf16)tile[tc + 1][cc];
    o[2] = (bf16)tile[tc + 2][cc];
    o[3] = (bf16)tile[tc + 3][cc];
    *(bf16x4*)(dst + (size_t)(c0 + cc) * R + (r0 + tc)) = o;
  }
}

// grouped GEMM: BM=256, BN=256, BK=64; 512 threads = 8 waves (2M x 4N),
// per-wave 128x64 output = acc[8][4]. Double-buffered LDS (128 KiB).
// T3+T4: each K-tile = 2 phases with staging units ALIGNED TO CONSUMPTION:
//   p0 (mi 0..3) reads A rows {0-63}U{128-191} = chunks {0,2} + B (all);
//   p1 (mi 4..7) reads A rows {64-127}U{192-255} = chunks {1,3}.
// Stage 3 phases ahead into just-freed regions:
//   p0(t) stages A13(t+1)   [2 gll]
//   p1(t) stages B,A02(t+2) [6 gll]
// Per-wave FIFO ledger (loads retire in issue order):
//   end p0(t): outstanding {A13(t)2, B_A02(t+1)6, A13(t+1)2}=10 -> vmcnt(8)
//     retires A13(t), exactly what p1(t) consumes.
//   end p1(t): outstanding {B_A02(t+1)6, A13(t+1)2, B_A02(t+2)6}=14 -> vmcnt(8)
//     retires B_A02(t+1), exactly what p0(t+1) consumes.
//   tails: vmcnt(2)/vmcnt(0) drain per the same ledger.
// One s_barrier per phase; asm "memory" clobbers fence compiler reordering.
// T2 swizzle (full-row, 8 chunks) as before; T5 setprio around MFMA.
// MODE 0: H[gr][n] = silu(acc + bias)  (bf16)
// MODE 1: atomicAdd(out[rows[gr]][n], coefs[gr] * (acc + addBias?bias:0))
template<int MODE>
__global__ __launch_bounds__(512, 1) void k_gemm(
    const bf16* __restrict__ A, const bf16* __restrict__ Bw,
    const float* __restrict__ bias, int bstride,
    bf16* __restrict__ H, float* __restrict__ Out, int addBias,
    const int* __restrict__ rows, const float* __restrict__ coefs,
    const int* __restrict__ meta, int KT, int NT) {
  int tidb = blockIdx.y;
  if (tidb >= meta[24]) return;
  int e = meta[64 + tidb];
  int row0 = meta[64 + MAXTILES + tidb];
  int n0 = blockIdx.x * 256;

  __shared__ __align__(16) bf16 As[2][256 * 64];   // 64 KiB
  __shared__ __align__(16) bf16 Bs[2][256 * 64];   // 64 KiB

  int t = threadIdx.x;              // 0..511
  int lane = t & 63;
  int w = t >> 6;                   // 0..7
  int wm = w >> 2, wn = w & 3;      // 2M x 4N

  // staging: thread t covers rows arow+{0,64,128,192} (chunks 0..3); global
  // k-chunk (t&7)^(arow&7) (pre-swizzled source); chunk i at LDS (t+i*512)*16B.
  int arow = t >> 3;                // 0..63
  int k8 = ((t & 7) ^ (arow & 7)) * 8;
  const bf16* Ab = A + (size_t)(row0 + arow) * KT + k8;
  const bf16* Bb = Bw + ((size_t)e * NT + n0 + arow) * KT + k8;
  size_t rstep = (size_t)64 * KT;
  int ldso = t * 8;                 // element offset

  f32x4 acc[8][4] = {};

  // B (4 gll) + A chunks {0,2} (rows arow, arow+128) -- consumed by p0
  auto stage_B_A02 = [&](int kt, int buf) {
    const bf16* a = Ab + kt;
    const bf16* b = Bb + kt;
    bf16* la = &As[buf][ldso];
    bf16* lb = &Bs[buf][ldso];
    async16(lb,         b);
    async16(lb + 4096,  b + rstep);
    async16(lb + 8192,  b + 2 * rstep);
    async16(lb + 12288, b + 3 * rstep);
    async16(la,         a);
    async16(la + 8192,  a + 2 * rstep);
  };
  // A chunks {1,3} (rows arow+64, arow+192) -- consumed by p1
  auto stage_A13 = [&](int kt, int buf) {
    const bf16* a = Ab + kt;
    bf16* la = &As[buf][ldso];
    async16(la + 4096,  a + rstep);
    async16(la + 12288, a + 3 * rstep);
  };

  int rA = (wm * 128 + (lane & 15)) * 64;   // wave A base row * 64
  int rB = (wn * 64 + (lane & 15)) * 64;    // wave B base row * 64
  int kx0 = ((lane >> 4) * 8) ^ ((lane & 7) * 8);
  int kx1 = kx0 ^ 32;

  int nt = KT >> 6;
  // prologue units in order: [B,A02(0)]6, [A13(0)]2, [B,A02(1)]6
  stage_B_A02(0, 0);
  stage_A13(0, 0);
  stage_B_A02(64, 1);
  asm volatile("s_waitcnt vmcnt(8)" ::: "memory");   // B,A02(0) landed
  __builtin_amdgcn_s_barrier();

  bf16x8 bfr[2][4];
  for (int tau = 0; tau < nt; ++tau) {
    int s = tau & 1;
    const bf16* Ap = &As[s][rA];
    const bf16* Bp = &Bs[s][rB];
    // ---------------- phase 0: B + A chunks{0,2}, MFMA mi 0..3 ------------
    {
      bf16x8 af[2][4];
#pragma unroll
      for (int ni = 0; ni < 4; ni++) {
        bfr[0][ni] = *(const bf16x8*)&Bp[ni * 1024 + kx0];
        bfr[1][ni] = *(const bf16x8*)&Bp[ni * 1024 + kx1];
      }
#pragma unroll
      for (int mi = 0; mi < 4; mi++) {
        af[0][mi] = *(const bf16x8*)&Ap[mi * 1024 + kx0];
        af[1][mi] = *(const bf16x8*)&Ap[mi * 1024 + kx1];
      }
      if (tau + 1 < nt) stage_A13((tau + 1) << 6, s ^ 1);
      __builtin_amdgcn_s_setprio(1);
#pragma unroll
      for (int ks = 0; ks < 2; ks++)
#pragma unroll
        for (int mi = 0; mi < 4; mi++)
#pragma unroll
          for (int ni = 0; ni < 4; ni++)
            acc[mi][ni] = __builtin_amdgcn_mfma_f32_16x16x32_bf16(
                af[ks][mi], bfr[ks][ni], acc[mi][ni], 0, 0, 0);
      __builtin_amdgcn_s_setprio(0);
    }
    // next phase consumes A13(tau) (oldest 2 outstanding)
    if (tau < nt - 1) asm volatile("s_waitcnt vmcnt(8)" ::: "memory");
    else              asm volatile("s_waitcnt vmcnt(0)" ::: "memory");
    __builtin_amdgcn_s_barrier();
    // ---------------- phase 1: A chunks{1,3}, MFMA mi 4..7 ----------------
    {
      bf16x8 af[2][4];
#pragma unroll
      for (int mi = 0; mi < 4; mi++) {
        af[0][mi] = *(const bf16x8*)&Ap[(mi + 4) * 1024 + kx0];
        af[1][mi] = *(const bf16x8*)&Ap[(mi + 4) * 1024 + kx1];
      }
      if (tau + 2 < nt) stage_B_A02((tau + 2) << 6, s);
      __builtin_amdgcn_s_setprio(1);
#pragma unroll
      for (int ks = 0; ks < 2; ks++)
#pragma unroll
        for (int mi = 0; mi < 4; mi++)
#pragma unroll
          for (int ni = 0; ni < 4; ni++)
            acc[mi + 4][ni] = __builtin_amdgcn_mfma_f32_16x16x32_bf16(
                af[ks][mi], bfr[ks][ni], acc[mi + 4][ni], 0, 0, 0);
      __builtin_amdgcn_s_setprio(0);
    }
    // next phase p0(tau+1) consumes B,A02(tau+1) (oldest 6 outstanding)
    if (tau < nt - 2)       asm volatile("s_waitcnt vmcnt(8)" ::: "memory");
    else if (tau == nt - 2) asm volatile("s_waitcnt vmcnt(2)" ::: "memory");
    else                    asm volatile("s_waitcnt vmcnt(0)" ::: "memory");
    __builtin_amdgcn_s_barrier();
  }

  int rq = (lane >> 4) * 4;
  int cq = lane & 15;
  float bv[4];
#pragma unroll
  for (int ni = 0; ni < 4; ni++)
    bv[ni] = bias[e * bstride + n0 + wn * 64 + ni * 16 + cq];

  if (MODE == 0) {
#pragma unroll
    for (int mi = 0; mi < 8; mi++) {
#pragma unroll
      for (int i = 0; i < 4; i++) {
        int gr = row0 + wm * 128 + mi * 16 + rq + i;
        bf16* hr = H + (size_t)gr * NT + n0 + wn * 64;
#pragma unroll
        for (int ni = 0; ni < 4; ni++) {
          float v = acc[mi][ni][i] + bv[ni];
          float s = v / (1.0f + __expf(-v));
          hr[ni * 16 + cq] = (bf16)s;
        }
      }
    }
  } else {
#pragma unroll
    for (int mi = 0; mi < 8; mi++) {
#pragma unroll
      for (int i = 0; i < 4; i++) {
        int gr = row0 + wm * 128 + mi * 16 + rq + i;
        int trow = rows[gr];
        if (trow < 0) continue;
        float cf = coefs[gr];
        float* orow = Out + (size_t)trow * DM + n0 + wn * 64;
#pragma unroll
        for (int ni = 0; ni < 4; ni++) {
          float v = acc[mi][ni][i];
          if (addBias) v += bv[ni];
          atomicAdd(&orow[ni * 16 + cq], cf * v);
        }
      }
    }
  }
}

extern "C" void kernel_launch(void* const* d_in, const int* in_sizes, int n_in,
                              void* d_out, int out_size, void* d_ws, size_t ws_size,
                              hipStream_t stream) {
  const float* x  = (const float*)d_in[0];
  const float* gw = (const float*)d_in[1];
  const float* gb = (const float*)d_in[2];
  const float* w1 = (const float*)d_in[3];
  const float* b1 = (const float*)d_in[4];
  const float* w2 = (const float*)d_in[5];
  const float* b2 = (const float*)d_in[6];
  float* out = (float*)d_out;

  // pick DF chunking so the workspace plan fits ws_size
  size_t smallB = (size_t)CAP * 4 * 2 + (size_t)TT * 2 * 4 * 2 + 8192 + 16 * 256;
  int nc = 8;
  for (int cand = 1; cand <= 8; cand <<= 1) {
    size_t dfc = DF / cand;
    size_t need = 2 * ((size_t)NE * dfc * DM * 2)   // w1tc + w2tc
                + (size_t)CAP * DM * 2              // xg
                + (size_t)CAP * dfc * 2             // h
                + smallB;
    if (need <= ws_size) { nc = cand; break; }
  }
  const int DFC = DF / nc;

  char* ws = (char*)d_ws;
  size_t off = 0;
  auto alloc = [&](size_t bytes) -> void* {
    void* p = ws + off;
    off += (bytes + 255) & ~(size_t)255;
    return p;
  };
  bf16* w1tc = (bf16*)alloc((size_t)NE * DFC * DM * 2);  // [E][DFC][DM]
  bf16* w2tc = (bf16*)alloc((size_t)NE * DM * DFC * 2);  // [E][DM][DFC]
  bf16* xg   = (bf16*)alloc((size_t)CAP * DM * 2);
  bf16* h    = (bf16*)alloc((size_t)CAP * DFC * 2);
  int* rows  = (int*)alloc((size_t)CAP * 4);
  float* cof = (float*)alloc((size_t)CAP * 4);
  int* sel   = (int*)alloc((size_t)TT * 2 * 4);
  float* cw  = (float*)alloc((size_t)TT * 2 * 4);
  int* meta  = (int*)alloc(8192);

  hipMemsetAsync(meta, 0, 256, stream);
  hipMemsetAsync(out, 0, (size_t)out_size * sizeof(float), stream);
  k_gate<<<TT / 4, 256, 0, stream>>>(x, gw, gb, sel, cw, meta);
  k_plan<<<1, 256, 0, stream>>>(meta, rows);
  k_scatter<<<TT / 256, 256, 0, stream>>>(sel, cw, meta, rows, cof);
  k_gather<<<CAP, 256, 0, stream>>>(x, rows, meta, xg);

  for (int c = 0; c < nc; c++) {
    const float* w1c = w1 + (size_t)c * DFC;        // [E][DM][DF] cols c*DFC..
    const float* w2c = w2 + (size_t)c * DFC * DM;   // [E][DF][DM] rows c*DFC..
    // w1 chunk: R=DM rows, DFC cols -> w1tc [E][DFC][DM]
    k_transcast<<<dim3(DFC / 64, DM / 64, NE), 256, 0, stream>>>(
        w1c, w1tc, DF, (size_t)DM * DF, (size_t)DFC * DM, DM);
    // w2 chunk: R=DFC rows, DM cols -> w2tc [E][DM][DFC]
    k_transcast<<<dim3(DM / 64, DFC / 64, NE), 256, 0, stream>>>(
        w2c, w2tc, DM, (size_t)DF * DM, (size_t)DM * DFC, DFC);
    // GEMM1: xg [CAP x DM] @ w1tc^T -> h (silu), N=DFC
    k_gemm<0><<<dim3(DFC / 256, MAXTILES), 512, 0, stream>>>(
        xg, w1tc, b1 + (size_t)c * DFC, DF, h, nullptr, 0, rows, cof, meta, DM, DFC);
    // GEMM2: h [CAP x DFC] @ w2tc^T -> atomic out, N=DM
    k_gemm<1><<<dim3(DM / 256, MAXTILES), 512, 0, stream>>>(
        h, w2tc, b2, DM, nullptr, out, (c == 0) ? 1 : 0, rows, cof, meta, DFC, DM);
  }
}

// Round 10
// 955.122 us; speedup vs baseline: 1.9634x; 1.5449x over previous
//
#include <hip/hip_runtime.h>
#include <hip/hip_bf16.h>
#include <stdint.h>

#define DM 1024
#define DF 4096
#define NE 8
#define TT 16384
#define MAXTILES 144          // 256-row tiles
#define CAP (MAXTILES * 256)  // 36864 padded rows max

typedef __bf16 bf16;
typedef __attribute__((ext_vector_type(8))) __bf16 bf16x8;
typedef __attribute__((ext_vector_type(4))) __bf16 bf16x4;
typedef __attribute__((ext_vector_type(4))) float f32x4;

#define AS1 __attribute__((address_space(1)))
#define AS3 __attribute__((address_space(3)))

__device__ __forceinline__ void async16(void* lds, const void* g) {
  __builtin_amdgcn_global_load_lds((const AS1 uint32_t*)g, (AS3 uint32_t*)lds, 16, 0, 0);
}

// ---------------- router: logits + top2 + softmax2 (pure f32, exact) --------
// (no atomics here anymore; counts via k_hist)
__global__ void k_gate(const float* __restrict__ x, const float* __restrict__ gw,
                       const float* __restrict__ gb,
                       int* __restrict__ sel, float* __restrict__ cw) {
  int gid = blockIdx.x * blockDim.x + threadIdx.x;
  int tok = gid >> 6;
  int lane = threadIdx.x & 63;
  const float* xr = x + (size_t)tok * DM;
  float l[8] = {0,0,0,0,0,0,0,0};
#pragma unroll
  for (int i = 0; i < DM / 64; i++) {
    int d = i * 64 + lane;
    float xv = xr[d];
    float4 gA = *(const float4*)(gw + d * 8);
    float4 gB = *(const float4*)(gw + d * 8 + 4);
    l[0] += xv * gA.x; l[1] += xv * gA.y; l[2] += xv * gA.z; l[3] += xv * gA.w;
    l[4] += xv * gB.x; l[5] += xv * gB.y; l[6] += xv * gB.z; l[7] += xv * gB.w;
  }
#pragma unroll
  for (int e = 0; e < 8; e++) {
    float v = l[e];
    v += __shfl_xor(v, 1);  v += __shfl_xor(v, 2);  v += __shfl_xor(v, 4);
    v += __shfl_xor(v, 8);  v += __shfl_xor(v, 16); v += __shfl_xor(v, 32);
    l[e] = v + gb[e];
  }
  if (lane == 0) {
    int e0 = 0;
#pragma unroll
    for (int e = 1; e < 8; e++) if (l[e] > l[e0]) e0 = e;
    int e1 = (e0 == 0) ? 1 : 0;
#pragma unroll
    for (int e = 0; e < 8; e++) if (e != e1 && e != e0 && l[e] > l[e1]) e1 = e;
    float t = expf(l[e1] - l[e0]);      // <= 1
    float c0 = 1.0f / (1.0f + t);
    float c1 = t / (1.0f + t);
    sel[2 * tok] = e0;  sel[2 * tok + 1] = e1;
    cw[2 * tok] = c0;   cw[2 * tok + 1] = c1;
  }
}

// per-block LDS histogram over sel -> 8 global atomics per block
__global__ void k_hist(const int* __restrict__ sel, int* __restrict__ meta) {
  __shared__ int h[8];
  if (threadIdx.x < 8) h[threadIdx.x] = 0;
  __syncthreads();
  int i = blockIdx.x * blockDim.x + threadIdx.x;   // over 2*TT entries
  atomicAdd(&h[sel[i]], 1);
  __syncthreads();
  if (threadIdx.x < 8) atomicAdd(&meta[threadIdx.x], h[threadIdx.x]);
}

// meta layout (ints): [0..7]=counts [8..15]=cursors [16..23]=segment offsets
//                     [24]=ntiles [25]=total_padded
//                     [64 .. 64+MAXTILES)  = tile expert id
//                     [64+MAXTILES .. )    = tile row0 (padded global row)
__global__ void k_plan(int* __restrict__ meta, int* __restrict__ rows) {
  if (threadIdx.x == 0) {
    int off = 0, nt = 0;
    for (int e = 0; e < NE; e++) {
      meta[16 + e] = off;
      int c = meta[e];
      int ntile = (c + 255) >> 8;
      for (int j = 0; j < ntile; j++) {
        meta[64 + nt] = e;
        meta[64 + MAXTILES + nt] = off + j * 256;
        nt++;
      }
      off += ntile * 256;
    }
    meta[24] = nt;
    meta[25] = off;
  }
  __syncthreads();
  for (int i = threadIdx.x; i < CAP; i += blockDim.x) rows[i] = -1;
}

// 128 tokens/block; LDS-rank + 8 global atomics per block
__global__ void k_scatter(const int* __restrict__ sel, const float* __restrict__ cw,
                          int* __restrict__ meta, int* __restrict__ rows,
                          float* __restrict__ coefs) {
  __shared__ int hcnt[8];
  __shared__ int hbase[8];
  if (threadIdx.x < 8) hcnt[threadIdx.x] = 0;
  __syncthreads();
  int slot = blockIdx.x * 256 + threadIdx.x;   // (token,k) slot over 2*TT
  int t = slot >> 1;
  int e = sel[slot];
  int r = atomicAdd(&hcnt[e], 1);
  __syncthreads();
  if (threadIdx.x < 8) hbase[threadIdx.x] = atomicAdd(&meta[8 + threadIdx.x], hcnt[threadIdx.x]);
  __syncthreads();
  int pos = meta[16 + e] + hbase[e] + r;
  rows[pos] = t;
  coefs[pos] = cw[slot];
}

__global__ void k_gather(const float* __restrict__ x, const int* __restrict__ rows,
                         const int* __restrict__ meta, bf16* __restrict__ xg) {
  int pos = blockIdx.x;
  if (pos >= meta[25]) return;
  int t = rows[pos];
  int c = threadIdx.x * 4;
  bf16x4 o;
  if (t >= 0) {
    float4 f = *(const float4*)(x + (size_t)t * DM + c);
    o[0] = (bf16)f.x; o[1] = (bf16)f.y; o[2] = (bf16)f.z; o[3] = (bf16)f.w;
  } else {
    o[0] = (bf16)0.0f; o[1] = (bf16)0.0f; o[2] = (bf16)0.0f; o[3] = (bf16)0.0f;
  }
  *(bf16x4*)(xg + (size_t)pos * DM + c) = o;
}

// reads src[z*srcE + (r0+r)*srcRS + c0+c]  -> dst[z*dstE + (c0+c)*R + r0+r] bf16
__global__ void k_transcast(const float* __restrict__ src, bf16* __restrict__ dst,
                            int srcRS, size_t srcE, size_t dstE, int R) {
  __shared__ float tile[64][65];
  src += blockIdx.z * srcE;
  dst += blockIdx.z * dstE;
  int r0 = blockIdx.y * 64, c0 = blockIdx.x * 64;
  int tr = threadIdx.x >> 4;          // 0..15
  int tc = (threadIdx.x & 15) * 4;    // 0..60
#pragma unroll
  for (int i = 0; i < 4; i++) {
    int r = tr + i * 16;
    float4 f = *(const float4*)(src + (size_t)(r0 + r) * srcRS + (c0 + tc));
    tile[r][tc] = f.x; tile[r][tc + 1] = f.y; tile[r][tc + 2] = f.z; tile[r][tc + 3] = f.w;
  }
  __syncthreads();
#pragma unroll
  for (int i = 0; i < 4; i++) {
    int cc = tr + i * 16;             // output row = input col
    bf16x4 o;
    o[0] = (bf16)tile[tc + 0][cc];
    o[1] = (bf16)tile[tc + 1][cc];
    o[2] = (bf16)tile[tc + 2][cc];
    o[3] = (bf16)tile[tc + 3][cc];
    *(bf16x4*)(dst + (size_t)(c0 + cc) * R + (r0 + tc)) = o;
  }
}

// grouped GEMM: BM=256, BN=256, BK=64; 512 threads = 8 waves (2M x 4N).
// Pipeline identical to R9 (2-phase counted-vmcnt, verified ledger).
// NEW: L2-locality block swizzle (T1-style, runtime tile count):
//   1-D grid; xcd = b&7 (consecutive blockIdx round-robin XCDs);
//   bijective chunk split (m204) over nact = ngx*T active blocks;
//   per-chunk order = (col-group g of 4 n-blocks) x (contiguous tiles) x col
//   -> co-resident blocks on an XCD share A-panels (4x) and a <=2MB
//   B working set (fits 4MiB L2).
// MODE 0: H[gr][n] = silu(acc + bias)  (bf16)
// MODE 1: atomicAdd(out[rows[gr]][n], coefs[gr] * (acc + addBias?bias:0))
template<int MODE>
__global__ __launch_bounds__(512, 1) void k_gemm(
    const bf16* __restrict__ A, const bf16* __restrict__ Bw,
    const float* __restrict__ bias, int bstride,
    bf16* __restrict__ H, float* __restrict__ Out, int addBias,
    const int* __restrict__ rows, const float* __restrict__ coefs,
    const int* __restrict__ meta, int KT, int NT) {
  int T = meta[24];
  int ngx = NT >> 8;
  int nact = ngx * T;
  int b = blockIdx.x;
  if (b >= nact) return;
  // invert hardware RR -> contiguous per-XCD chunk (bijective, m204)
  int q = nact >> 3, rr = nact & 7;
  int xcd = b & 7, i = b >> 3;
  int j = xcd * q + (xcd < rr ? xcd : rr) + i;
  int gT4 = T << 2;
  int g = j / gT4;
  int rem = j - g * gT4;
  int tidb = rem >> 2;                 // tile index (contiguous within chunk)
  int xnb = (g << 2) + (rem & 3);      // n-block
  int e = meta[64 + tidb];
  int row0 = meta[64 + MAXTILES + tidb];
  int n0 = xnb << 8;

  __shared__ __align__(16) bf16 As[2][256 * 64];   // 64 KiB
  __shared__ __align__(16) bf16 Bs[2][256 * 64];   // 64 KiB

  int t = threadIdx.x;              // 0..511
  int lane = t & 63;
  int w = t >> 6;                   // 0..7
  int wm = w >> 2, wn = w & 3;      // 2M x 4N

  // staging: thread t covers rows arow+{0,64,128,192} (chunks 0..3); global
  // k-chunk (t&7)^(arow&7) (pre-swizzled source); chunk i at LDS (t+i*512)*16B.
  int arow = t >> 3;                // 0..63
  int k8 = ((t & 7) ^ (arow & 7)) * 8;
  const bf16* Ab = A + (size_t)(row0 + arow) * KT + k8;
  const bf16* Bb = Bw + ((size_t)e * NT + n0 + arow) * KT + k8;
  size_t rstep = (size_t)64 * KT;
  int ldso = t * 8;                 // element offset

  f32x4 acc[8][4] = {};

  // B (4 gll) + A chunks {0,2} (rows arow, arow+128) -- consumed by p0
  auto stage_B_A02 = [&](int kt, int buf) {
    const bf16* a = Ab + kt;
    const bf16* b2 = Bb + kt;
    bf16* la = &As[buf][ldso];
    bf16* lb = &Bs[buf][ldso];
    async16(lb,         b2);
    async16(lb + 4096,  b2 + rstep);
    async16(lb + 8192,  b2 + 2 * rstep);
    async16(lb + 12288, b2 + 3 * rstep);
    async16(la,         a);
    async16(la + 8192,  a + 2 * rstep);
  };
  // A chunks {1,3} (rows arow+64, arow+192) -- consumed by p1
  auto stage_A13 = [&](int kt, int buf) {
    const bf16* a = Ab + kt;
    bf16* la = &As[buf][ldso];
    async16(la + 4096,  a + rstep);
    async16(la + 12288, a + 3 * rstep);
  };

  int rA = (wm * 128 + (lane & 15)) * 64;   // wave A base row * 64
  int rB = (wn * 64 + (lane & 15)) * 64;    // wave B base row * 64
  int kx0 = ((lane >> 4) * 8) ^ ((lane & 7) * 8);
  int kx1 = kx0 ^ 32;

  int nt = KT >> 6;
  // prologue units in order: [B,A02(0)]6, [A13(0)]2, [B,A02(1)]6
  stage_B_A02(0, 0);
  stage_A13(0, 0);
  stage_B_A02(64, 1);
  asm volatile("s_waitcnt vmcnt(8)" ::: "memory");   // B,A02(0) landed
  __builtin_amdgcn_s_barrier();

  bf16x8 bfr[2][4];
  for (int tau = 0; tau < nt; ++tau) {
    int s = tau & 1;
    const bf16* Ap = &As[s][rA];
    const bf16* Bp = &Bs[s][rB];
    // ---------------- phase 0: B + A chunks{0,2}, MFMA mi 0..3 ------------
    {
      bf16x8 af[2][4];
#pragma unroll
      for (int ni = 0; ni < 4; ni++) {
        bfr[0][ni] = *(const bf16x8*)&Bp[ni * 1024 + kx0];
        bfr[1][ni] = *(const bf16x8*)&Bp[ni * 1024 + kx1];
      }
#pragma unroll
      for (int mi = 0; mi < 4; mi++) {
        af[0][mi] = *(const bf16x8*)&Ap[mi * 1024 + kx0];
        af[1][mi] = *(const bf16x8*)&Ap[mi * 1024 + kx1];
      }
      if (tau + 1 < nt) stage_A13((tau + 1) << 6, s ^ 1);
      __builtin_amdgcn_s_setprio(1);
#pragma unroll
      for (int ks = 0; ks < 2; ks++)
#pragma unroll
        for (int mi = 0; mi < 4; mi++)
#pragma unroll
          for (int ni = 0; ni < 4; ni++)
            acc[mi][ni] = __builtin_amdgcn_mfma_f32_16x16x32_bf16(
                af[ks][mi], bfr[ks][ni], acc[mi][ni], 0, 0, 0);
      __builtin_amdgcn_s_setprio(0);
    }
    // next phase consumes A13(tau) (oldest 2 outstanding)
    if (tau < nt - 1) asm volatile("s_waitcnt vmcnt(8)" ::: "memory");
    else              asm volatile("s_waitcnt vmcnt(0)" ::: "memory");
    __builtin_amdgcn_s_barrier();
    // ---------------- phase 1: A chunks{1,3}, MFMA mi 4..7 ----------------
    {
      bf16x8 af[2][4];
#pragma unroll
      for (int mi = 0; mi < 4; mi++) {
        af[0][mi] = *(const bf16x8*)&Ap[(mi + 4) * 1024 + kx0];
        af[1][mi] = *(const bf16x8*)&Ap[(mi + 4) * 1024 + kx1];
      }
      if (tau + 2 < nt) stage_B_A02((tau + 2) << 6, s);
      __builtin_amdgcn_s_setprio(1);
#pragma unroll
      for (int ks = 0; ks < 2; ks++)
#pragma unroll
        for (int mi = 0; mi < 4; mi++)
#pragma unroll
          for (int ni = 0; ni < 4; ni++)
            acc[mi + 4][ni] = __builtin_amdgcn_mfma_f32_16x16x32_bf16(
                af[ks][mi], bfr[ks][ni], acc[mi + 4][ni], 0, 0, 0);
      __builtin_amdgcn_s_setprio(0);
    }
    // next phase p0(tau+1) consumes B,A02(tau+1) (oldest 6 outstanding)
    if (tau < nt - 2)       asm volatile("s_waitcnt vmcnt(8)" ::: "memory");
    else if (tau == nt - 2) asm volatile("s_waitcnt vmcnt(2)" ::: "memory");
    else                    asm volatile("s_waitcnt vmcnt(0)" ::: "memory");
    __builtin_amdgcn_s_barrier();
  }

  int rq = (lane >> 4) * 4;
  int cq = lane & 15;
  float bv[4];
#pragma unroll
  for (int ni = 0; ni < 4; ni++)
    bv[ni] = bias[e * bstride + n0 + wn * 64 + ni * 16 + cq];

  if (MODE == 0) {
#pragma unroll
    for (int mi = 0; mi < 8; mi++) {
#pragma unroll
      for (int i2 = 0; i2 < 4; i2++) {
        int gr = row0 + wm * 128 + mi * 16 + rq + i2;
        bf16* hr = H + (size_t)gr * NT + n0 + wn * 64;
#pragma unroll
        for (int ni = 0; ni < 4; ni++) {
          float v = acc[mi][ni][i2] + bv[ni];
          float sg = v / (1.0f + __expf(-v));
          hr[ni * 16 + cq] = (bf16)sg;
        }
      }
    }
  } else {
#pragma unroll
    for (int mi = 0; mi < 8; mi++) {
#pragma unroll
      for (int i2 = 0; i2 < 4; i2++) {
        int gr = row0 + wm * 128 + mi * 16 + rq + i2;
        int trow = rows[gr];
        if (trow < 0) continue;
        float cf = coefs[gr];
        float* orow = Out + (size_t)trow * DM + n0 + wn * 64;
#pragma unroll
        for (int ni = 0; ni < 4; ni++) {
          float v = acc[mi][ni][i2];
          if (addBias) v += bv[ni];
          atomicAdd(&orow[ni * 16 + cq], cf * v);
        }
      }
    }
  }
}

extern "C" void kernel_launch(void* const* d_in, const int* in_sizes, int n_in,
                              void* d_out, int out_size, void* d_ws, size_t ws_size,
                              hipStream_t stream) {
  const float* x  = (const float*)d_in[0];
  const float* gw = (const float*)d_in[1];
  const float* gb = (const float*)d_in[2];
  const float* w1 = (const float*)d_in[3];
  const float* b1 = (const float*)d_in[4];
  const float* w2 = (const float*)d_in[5];
  const float* b2 = (const float*)d_in[6];
  float* out = (float*)d_out;

  // pick DF chunking so the workspace plan fits ws_size
  size_t smallB = (size_t)CAP * 4 * 2 + (size_t)TT * 2 * 4 * 2 + 8192 + 16 * 256;
  int nc = 8;
  for (int cand = 1; cand <= 8; cand <<= 1) {
    size_t dfc = DF / cand;
    size_t need = 2 * ((size_t)NE * dfc * DM * 2)   // w1tc + w2tc
                + (size_t)CAP * DM * 2              // xg
                + (size_t)CAP * dfc * 2             // h
                + smallB;
    if (need <= ws_size) { nc = cand; break; }
  }
  const int DFC = DF / nc;

  char* ws = (char*)d_ws;
  size_t off = 0;
  auto alloc = [&](size_t bytes) -> void* {
    void* p = ws + off;
    off += (bytes + 255) & ~(size_t)255;
    return p;
  };
  bf16* w1tc = (bf16*)alloc((size_t)NE * DFC * DM * 2);  // [E][DFC][DM]
  bf16* w2tc = (bf16*)alloc((size_t)NE * DM * DFC * 2);  // [E][DM][DFC]
  bf16* xg   = (bf16*)alloc((size_t)CAP * DM * 2);
  bf16* h    = (bf16*)alloc((size_t)CAP * DFC * 2);
  int* rows  = (int*)alloc((size_t)CAP * 4);
  float* cof = (float*)alloc((size_t)CAP * 4);
  int* sel   = (int*)alloc((size_t)TT * 2 * 4);
  float* cw  = (float*)alloc((size_t)TT * 2 * 4);
  int* meta  = (int*)alloc(8192);

  hipMemsetAsync(meta, 0, 256, stream);
  hipMemsetAsync(out, 0, (size_t)out_size * sizeof(float), stream);
  k_gate<<<TT / 4, 256, 0, stream>>>(x, gw, gb, sel, cw);
  k_hist<<<2 * TT / 256, 256, 0, stream>>>(sel, meta);
  k_plan<<<1, 256, 0, stream>>>(meta, rows);
  k_scatter<<<2 * TT / 256, 256, 0, stream>>>(sel, cw, meta, rows, cof);
  k_gather<<<CAP, 256, 0, stream>>>(x, rows, meta, xg);

  for (int c = 0; c < nc; c++) {
    const float* w1c = w1 + (size_t)c * DFC;        // [E][DM][DF] cols c*DFC..
    const float* w2c = w2 + (size_t)c * DFC * DM;   // [E][DF][DM] rows c*DFC..
    // w1 chunk: R=DM rows, DFC cols -> w1tc [E][DFC][DM]
    k_transcast<<<dim3(DFC / 64, DM / 64, NE), 256, 0, stream>>>(
        w1c, w1tc, DF, (size_t)DM * DF, (size_t)DFC * DM, DM);
    // w2 chunk: R=DFC rows, DM cols -> w2tc [E][DM][DFC]
    k_transcast<<<dim3(DM / 64, DFC / 64, NE), 256, 0, stream>>>(
        w2c, w2tc, DM, (size_t)DF * DM, (size_t)DM * DFC, DFC);
    // GEMM1: xg [CAP x DM] @ w1tc^T -> h (silu), N=DFC
    k_gemm<0><<<(DFC / 256) * MAXTILES, 512, 0, stream>>>(
        xg, w1tc, b1 + (size_t)c * DFC, DF, h, nullptr, 0, rows, cof, meta, DM, DFC);
    // GEMM2: h [CAP x DFC] @ w2tc^T -> atomic out, N=DM
    k_gemm<1><<<(DM / 256) * MAXTILES, 512, 0, stream>>>(
        h, w2tc, b2, DM, nullptr, out, (c == 0) ? 1 : 0, rows, cof, meta, DFC, DM);
  }
}